// Round 7
// baseline (72.207 us; speedup 1.0000x reference)
//
#include <hip/hip_runtime.h>

// Dihedral2Coord — R6 kernel body repeated 6x in-kernel (MEASUREMENT ROUND).
// Iteration-opaque pointer offsets (empty asm) force all 6 iterations to
// re-execute loads/compute/stores identically -> rocprof row shows ~6x the
// true kernel time, separating it from any fixed per-replay harness cost.
// Output is written 6 times with identical values: deterministic, idempotent.

#define NK 128
#define NM 512
#define NMOL 4096
#define TPB 256
#define MPW 4     // molecules (waves) per block
#define REPS 6

struct Aff { float qw, qx, qy, qz, tx, ty, tz; };

__device__ __forceinline__ void qrot(float qw, float qx, float qy, float qz,
                                     float vx, float vy, float vz,
                                     float& ox, float& oy, float& oz) {
    const float ux = qy*vz - qz*vy + qw*vx;
    const float uy = qz*vx - qx*vz + qw*vy;
    const float uz = qx*vy - qy*vx + qw*vz;
    ox = vx + 2.f*(qy*uz - qz*uy);
    oy = vy + 2.f*(qz*ux - qx*uz);
    oz = vz + 2.f*(qx*uy - qy*ux);
}

__device__ __forceinline__ Aff aff_compose(const Aff& Q, const Aff& P) {
    Aff r;
    r.qw = Q.qw*P.qw - Q.qx*P.qx - Q.qy*P.qy - Q.qz*P.qz;
    r.qx = Q.qw*P.qx + Q.qx*P.qw + Q.qy*P.qz - Q.qz*P.qy;
    r.qy = Q.qw*P.qy - Q.qx*P.qz + Q.qy*P.qw + Q.qz*P.qx;
    r.qz = Q.qw*P.qz + Q.qx*P.qy - Q.qy*P.qx + Q.qz*P.qw;
    float rx, ry, rz;
    qrot(Q.qw, Q.qx, Q.qy, Q.qz, P.tx, P.ty, P.tz, rx, ry, rz);
    r.tx = rx + Q.tx; r.ty = ry + Q.ty; r.tz = rz + Q.tz;
    return r;
}

__device__ __forceinline__ void qnorm(Aff& a) {
    const float r = rsqrtf(a.qw*a.qw + a.qx*a.qx + a.qy*a.qy + a.qz*a.qz);
    a.qw *= r; a.qx *= r; a.qy *= r; a.qz *= r;
}

__device__ __forceinline__ Aff make_step(float c, float s,
                                         float ax, float ay, float az,
                                         float px, float py, float pz) {
    const float hc = sqrtf(fmaxf(0.f, 0.5f*(1.f + c)));
    const float hs = copysignf(sqrtf(fmaxf(0.f, 0.5f*(1.f - c))), s);
    Aff b; b.qw = hc; b.qx = hs*ax; b.qy = hs*ay; b.qz = hs*az;
    float rx, ry, rz;
    qrot(b.qw, b.qx, b.qy, b.qz, px, py, pz, rx, ry, rz);
    b.tx = px - rx; b.ty = py - ry; b.tz = pz - rz;
    return b;
}

#define SHFL_AFF_UP(D, S, off)                                           \
    D.qw = __shfl_up(S.qw, off, 64); D.qx = __shfl_up(S.qx, off, 64);    \
    D.qy = __shfl_up(S.qy, off, 64); D.qz = __shfl_up(S.qz, off, 64);    \
    D.tx = __shfl_up(S.tx, off, 64); D.ty = __shfl_up(S.ty, off, 64);    \
    D.tz = __shfl_up(S.tz, off, 64);

__global__ __launch_bounds__(TPB, 4) void dihedral_fused_x6_kernel(
    const float* __restrict__ theta,  // (NMOL, NK)
    const float* __restrict__ pos0,   // (NMOL, NM, 3)
    float* __restrict__ out)          // (NMOL, NM, 3)
{
    const int tid  = threadIdx.x;
    const int lane = tid & 63;
    const int wid  = tid >> 6;
    const int mol  = blockIdx.x * MPW + wid;

    __shared__ float sA[MPW][400];   // per-wave: pos0 atoms 0..131
    __shared__ float sO[MPW][400];   // per-wave: final atoms 0..131

    for (int rep = 0; rep < REPS; ++rep) {
        // opaque zero: compiler cannot hoist loads / elide stores across reps
        int zero = 0;
        asm volatile("" : "+v"(zero));
        const float4* __restrict__ pb4 = (const float4*)(pos0 + (size_t)mol * (NM*3)) + zero;
        float4*       __restrict__ ob4 = (float4*)(out  + (size_t)mol * (NM*3)) + zero;
        const float2* __restrict__ tb2 = (const float2*)(theta + (size_t)mol * NK) + zero;

        // ---- issue ALL global loads up front ----
        float4 h0 = pb4[lane];
        float4 h1; if (lane < 35) h1 = pb4[64 + lane];
        const float2 th2 = tb2[lane];
        float4 Ta0, Ta1, Ta2, Tb0, Tb1, Tb2;
        { const int b = 99 + 3*lane; Ta0 = pb4[b]; Ta1 = pb4[b+1]; Ta2 = pb4[b+2]; }
        const bool hasB = (lane < 31);   // tasks 64..94
        if (hasB) { const int b = 99 + 3*(64 + lane); Tb0 = pb4[b]; Tb1 = pb4[b+1]; Tb2 = pb4[b+2]; }

        // stage head into this wave's LDS slice (same-wave DS ordering)
        float4* sA4 = (float4*)sA[wid];
        sA4[lane] = h0;
        if (lane < 35) sA4[64 + lane] = h1;

        // lane k: atoms 2k..2k+4 (15 floats)
        float A[16];
        const float2* ap2 = (const float2*)&sA[wid][lane * 6];
        #pragma unroll
        for (int i = 0; i < 7; ++i) { const float2 v = ap2[i]; A[2*i] = v.x; A[2*i+1] = v.y; }
        A[14] = sA[wid][lane * 6 + 14];

        // ---- dihedral geometry for steps 2k, 2k+1 (shared normals) ----
        const float v01x=A[3]-A[0],  v01y=A[4]-A[1],   v01z=A[5]-A[2];
        const float v12x=A[6]-A[3],  v12y=A[7]-A[4],   v12z=A[8]-A[5];
        const float v23x=A[9]-A[6],  v23y=A[10]-A[7],  v23z=A[11]-A[8];
        const float v34x=A[12]-A[9], v34y=A[13]-A[10], v34z=A[14]-A[11];
        const float n1x=v01y*v12z-v01z*v12y, n1y=v01z*v12x-v01x*v12z, n1z=v01x*v12y-v01y*v12x;
        const float n2x=v12y*v23z-v12z*v23y, n2y=v12z*v23x-v12x*v23z, n2z=v12x*v23y-v12y*v23x;
        const float n3x=v23y*v34z-v23z*v34y, n3y=v23z*v34x-v23x*v34z, n3z=v23x*v34y-v23y*v34x;
        const float mex=n1y*v12z-n1z*v12y,  mey=n1z*v12x-n1x*v12z,  mez=n1x*v12y-n1y*v12x;
        const float mox=n2y*v23z-n2z*v23y,  moy=n2z*v23x-n2x*v23z,  moz=n2x*v23y-n2y*v23x;
        const float L1=n1x*n1x+n1y*n1y+n1z*n1z;
        const float L2=n2x*n2x+n2y*n2y+n2z*n2z;
        const float L3=n3x*n3x+n3y*n3y+n3z*n3z;
        const float Lme=mex*mex+mey*mey+mez*mez;
        const float Lmo=mox*mox+moy*moy+moz*moz;

        float sphE = (mex*n2x+mey*n2y+mez*n2z) * rsqrtf(Lme*L2);
        float cphE = (n1x*n2x+n1y*n2y+n1z*n2z) * rsqrtf(L1*L2);
        { const float rn = rsqrtf(sphE*sphE + cphE*cphE); sphE *= rn; cphE *= rn; }
        float sthE, cthE; sincosf(th2.x, &sthE, &cthE);
        const float cE = cthE*cphE - sthE*sphE;
        const float sE = sthE*cphE + cthE*sphE;
        const float LjkE = v12x*v12x+v12y*v12y+v12z*v12z;
        const float invE = rsqrtf(fmaxf(LjkE, 1e-24f));
        Aff Bev = make_step(cE, sE, v12x*invE, v12y*invE, v12z*invE, A[3], A[4], A[5]);

        float sphO = (mox*n3x+moy*n3y+moz*n3z) * rsqrtf(Lmo*L3);
        float cphO = (n2x*n3x+n2y*n3y+n2z*n3z) * rsqrtf(L2*L3);
        { const float rn = rsqrtf(sphO*sphO + cphO*cphO); sphO *= rn; cphO *= rn; }
        float sthO, cthO; sincosf(th2.y, &sthO, &cthO);
        const float cO = cthO*cphO - sthO*sphO;
        const float sO_ = sthO*cphO + cthO*sphO;
        const float LjkO = v23x*v23x+v23y*v23y+v23z*v23z;
        const float invO = rsqrtf(fmaxf(LjkO, 1e-24f));
        Aff Bod = make_step(cO, sO_, v23x*invO, v23y*invO, v23z*invO, A[6], A[7], A[8]);

        Aff S = aff_compose(Bev, Bod);   // C_k = B_{2k}∘B_{2k+1}

        // ---- wave-inclusive scan ----
        #pragma unroll
        for (int off = 1; off < 64; off <<= 1) {
            Aff Q; SHFL_AFF_UP(Q, S, off);
            if (lane >= off) S = aff_compose(Q, S);
        }
        Aff E; SHFL_AFF_UP(E, S, 1);
        if (lane == 0) { E.qw = 1.f; E.qx = E.qy = E.qz = 0.f; E.tx = E.ty = E.tz = 0.f; }
        Aff Pe = aff_compose(E, Bev);    // P_{2k}
        qnorm(Pe); qnorm(S);

        // ---- emit head atoms into this wave's sO slice ----
        {
            float ox, oy, oz;
            float* op = &sO[wid][lane * 6 + 9];
            qrot(Pe.qw, Pe.qx, Pe.qy, Pe.qz, A[9], A[10], A[11], ox, oy, oz);
            op[0] = ox + Pe.tx; op[1] = oy + Pe.ty; op[2] = oz + Pe.tz;
            qrot(S.qw, S.qx, S.qy, S.qz, A[12], A[13], A[14], ox, oy, oz);
            op[3] = ox + S.tx;  op[4] = oy + S.ty;  op[5] = oz + S.tz;
        }
        if (lane < 9) sO[wid][lane] = sA[wid][lane];
        if (lane == 63) {
            float ox, oy, oz;
            qrot(S.qw, S.qx, S.qy, S.qz, sA[wid][393], sA[wid][394], sA[wid][395], ox, oy, oz);
            sO[wid][393] = ox + S.tx; sO[wid][394] = oy + S.ty; sO[wid][395] = oz + S.tz;
        }

        // ---- F = P_127 broadcast ----
        Aff F;
        F.qw = __shfl(S.qw, 63, 64); F.qx = __shfl(S.qx, 63, 64);
        F.qy = __shfl(S.qy, 63, 64); F.qz = __shfl(S.qz, 63, 64);
        F.tx = __shfl(S.tx, 63, 64); F.ty = __shfl(S.ty, 63, 64);
        F.tz = __shfl(S.tz, 63, 64);
        const float f00 = 1.f - 2.f*(F.qy*F.qy + F.qz*F.qz);
        const float f01 = 2.f*(F.qx*F.qy - F.qw*F.qz);
        const float f02 = 2.f*(F.qx*F.qz + F.qw*F.qy);
        const float f10 = 2.f*(F.qx*F.qy + F.qw*F.qz);
        const float f11 = 1.f - 2.f*(F.qx*F.qx + F.qz*F.qz);
        const float f12 = 2.f*(F.qy*F.qz - F.qw*F.qx);
        const float f20 = 2.f*(F.qx*F.qz - F.qw*F.qy);
        const float f21 = 2.f*(F.qy*F.qz + F.qw*F.qx);
        const float f22 = 1.f - 2.f*(F.qx*F.qx + F.qy*F.qy);

        // ---- store head ----
        const float4* sO4 = (const float4*)sO[wid];
        ob4[lane] = sO4[lane];
        if (lane < 35) ob4[64 + lane] = sO4[64 + lane];

        // ---- tail ----
        #define TAIL_EMIT(b, va, vb, vc)                                          \
        do {                                                                      \
            const float x0=va.x, y0=va.y, z0=va.z;                                \
            const float x1=va.w, y1=vb.x, z1=vb.y;                                \
            const float x2=vb.z, y2=vb.w, z2=vc.x;                                \
            const float x3=vc.y, y3=vc.z, z3=vc.w;                                \
            float4 o0, o1, o2;                                                    \
            o0.x = f00*x0+f01*y0+f02*z0+F.tx; o0.y = f10*x0+f11*y0+f12*z0+F.ty;   \
            o0.z = f20*x0+f21*y0+f22*z0+F.tz; o0.w = f00*x1+f01*y1+f02*z1+F.tx;   \
            o1.x = f10*x1+f11*y1+f12*z1+F.ty; o1.y = f20*x1+f21*y1+f22*z1+F.tz;   \
            o1.z = f00*x2+f01*y2+f02*z2+F.tx; o1.w = f10*x2+f11*y2+f12*z2+F.ty;   \
            o2.x = f20*x2+f21*y2+f22*z2+F.tz; o2.y = f00*x3+f01*y3+f02*z3+F.tx;   \
            o2.z = f10*x3+f11*y3+f12*z3+F.ty; o2.w = f20*x3+f21*y3+f22*z3+F.tz;   \
            ob4[(b)] = o0; ob4[(b)+1] = o1; ob4[(b)+2] = o2;                      \
        } while (0)

        TAIL_EMIT(99 + 3*lane, Ta0, Ta1, Ta2);
        if (hasB) TAIL_EMIT(99 + 3*(64 + lane), Tb0, Tb1, Tb2);
        #undef TAIL_EMIT

        // LDS reuse across reps is safe: same wave rewrites its own slice
        // before reading it, in program order.
    }
}

extern "C" void kernel_launch(void* const* d_in, const int* in_sizes, int n_in,
                              void* d_out, int out_size, void* d_ws, size_t ws_size,
                              hipStream_t stream) {
    const float* theta = (const float*)d_in[0];  // input (N,K) fp32
    const float* pos0  = (const float*)d_in[1];  // pos0 (N,M,3) fp32
    float* out = (float*)d_out;                  // (N,M,3) fp32
    dihedral_fused_x6_kernel<<<NMOL / MPW, TPB, 0, stream>>>(theta, pos0, out);
}

// Round 8
// 28.523 us; speedup vs baseline: 2.5315x; 2.5315x over previous
//
#include <hip/hip_runtime.h>

// Dihedral2Coord — one molecule per BLOCK (192 thr): wave0 = quat prefix scan,
// waves 1-2 = tail streaming. Tail loads issue before the barrier so their
// cold-HBM latency hides under wave0's scan; ~10 blocks/CU pipeline freely.
//
// final[m] = P_{m-3}(pos0[m]); P_k = B_0∘...∘B_k with B_k the LOCAL-frame
// step rotation (dihedrals are rigid-invariant -> phi_k from pos0 alone).

#define NK 128
#define NM 512
#define NMOL 4096
#define TPB 192

struct Aff { float qw, qx, qy, qz, tx, ty, tz; };

__device__ __forceinline__ void qrot(float qw, float qx, float qy, float qz,
                                     float vx, float vy, float vz,
                                     float& ox, float& oy, float& oz) {
    const float ux = qy*vz - qz*vy + qw*vx;
    const float uy = qz*vx - qx*vz + qw*vy;
    const float uz = qx*vy - qy*vx + qw*vz;
    ox = vx + 2.f*(qy*uz - qz*uy);
    oy = vy + 2.f*(qz*ux - qx*uz);
    oz = vz + 2.f*(qx*uy - qy*ux);
}

__device__ __forceinline__ Aff aff_compose(const Aff& Q, const Aff& P) {
    Aff r;
    r.qw = Q.qw*P.qw - Q.qx*P.qx - Q.qy*P.qy - Q.qz*P.qz;
    r.qx = Q.qw*P.qx + Q.qx*P.qw + Q.qy*P.qz - Q.qz*P.qy;
    r.qy = Q.qw*P.qy - Q.qx*P.qz + Q.qy*P.qw + Q.qz*P.qx;
    r.qz = Q.qw*P.qz + Q.qx*P.qy - Q.qy*P.qx + Q.qz*P.qw;
    float rx, ry, rz;
    qrot(Q.qw, Q.qx, Q.qy, Q.qz, P.tx, P.ty, P.tz, rx, ry, rz);
    r.tx = rx + Q.tx; r.ty = ry + Q.ty; r.tz = rz + Q.tz;
    return r;
}

__device__ __forceinline__ void qnorm(Aff& a) {
    const float r = rsqrtf(a.qw*a.qw + a.qx*a.qx + a.qy*a.qy + a.qz*a.qz);
    a.qw *= r; a.qx *= r; a.qy *= r; a.qz *= r;
}

__device__ __forceinline__ Aff make_step(float c, float s,
                                         float ax, float ay, float az,
                                         float px, float py, float pz) {
    const float hc = sqrtf(fmaxf(0.f, 0.5f*(1.f + c)));
    const float hs = copysignf(sqrtf(fmaxf(0.f, 0.5f*(1.f - c))), s);
    Aff b; b.qw = hc; b.qx = hs*ax; b.qy = hs*ay; b.qz = hs*az;
    float rx, ry, rz;
    qrot(b.qw, b.qx, b.qy, b.qz, px, py, pz, rx, ry, rz);
    b.tx = px - rx; b.ty = py - ry; b.tz = pz - rz;
    return b;
}

#define SHFL_AFF_UP(D, S, off)                                           \
    D.qw = __shfl_up(S.qw, off, 64); D.qx = __shfl_up(S.qx, off, 64);    \
    D.qy = __shfl_up(S.qy, off, 64); D.qz = __shfl_up(S.qz, off, 64);    \
    D.tx = __shfl_up(S.tx, off, 64); D.ty = __shfl_up(S.ty, off, 64);    \
    D.tz = __shfl_up(S.tz, off, 64);

__global__ __launch_bounds__(TPB, 8) void dihedral_block_kernel(
    const float* __restrict__ theta,  // (NMOL, NK)
    const float* __restrict__ pos0,   // (NMOL, NM, 3)
    float* __restrict__ out)          // (NMOL, NM, 3)
{
    const int tid  = threadIdx.x;
    const int lane = tid & 63;
    const int wid  = tid >> 6;
    const int mol  = blockIdx.x;
    const float4* __restrict__ pb4 = (const float4*)(pos0 + (size_t)mol * (NM*3));
    float4*       __restrict__ ob4 = (float4*)(out  + (size_t)mol * (NM*3));

    __shared__ float sA[400];   // pos0 atoms 0..131
    __shared__ float sO[400];   // final atoms 0..131
    __shared__ float sF[12];    // F = P_127 as 3x4 matrix rows

    // ---- waves 1-2: issue all tail loads up front (hide cold HBM latency
    //      under wave0's scan), then wait at the barrier ----
    const int t = tid - 64;                 // 0..127 on waves 1-2
    const bool isTail = (wid > 0) && (t < 95);
    float4 T0, T1, T2;
    if (isTail) { const int b = 99 + 3*t; T0 = pb4[b]; T1 = pb4[b+1]; T2 = pb4[b+2]; }

    if (wid == 0) {
        // ---- wave 0: stage head, build B's, scan, emit head atoms ----
        float4* sA4 = (float4*)sA;
        float4 h0 = pb4[lane];
        float4 h1; if (lane < 35) h1 = pb4[64 + lane];
        const float2 th2 = ((const float2*)(theta + (size_t)mol * NK))[lane];
        sA4[lane] = h0;
        if (lane < 35) sA4[64 + lane] = h1;
        // same-wave DS ordering: no barrier needed before reading sA

        float A[16];
        const float2* ap2 = (const float2*)&sA[lane * 6];
        #pragma unroll
        for (int i = 0; i < 7; ++i) { const float2 v = ap2[i]; A[2*i] = v.x; A[2*i+1] = v.y; }
        A[14] = sA[lane * 6 + 14];

        // dihedral geometry for steps 2k, 2k+1 (shared normals)
        const float v01x=A[3]-A[0],  v01y=A[4]-A[1],   v01z=A[5]-A[2];
        const float v12x=A[6]-A[3],  v12y=A[7]-A[4],   v12z=A[8]-A[5];
        const float v23x=A[9]-A[6],  v23y=A[10]-A[7],  v23z=A[11]-A[8];
        const float v34x=A[12]-A[9], v34y=A[13]-A[10], v34z=A[14]-A[11];
        const float n1x=v01y*v12z-v01z*v12y, n1y=v01z*v12x-v01x*v12z, n1z=v01x*v12y-v01y*v12x;
        const float n2x=v12y*v23z-v12z*v23y, n2y=v12z*v23x-v12x*v23z, n2z=v12x*v23y-v12y*v23x;
        const float n3x=v23y*v34z-v23z*v34y, n3y=v23z*v34x-v23x*v34z, n3z=v23x*v34y-v23y*v34x;
        const float mex=n1y*v12z-n1z*v12y,  mey=n1z*v12x-n1x*v12z,  mez=n1x*v12y-n1y*v12x;
        const float mox=n2y*v23z-n2z*v23y,  moy=n2z*v23x-n2x*v23z,  moz=n2x*v23y-n2y*v23x;
        const float L1=n1x*n1x+n1y*n1y+n1z*n1z;
        const float L2=n2x*n2x+n2y*n2y+n2z*n2z;
        const float L3=n3x*n3x+n3y*n3y+n3z*n3z;
        const float Lme=mex*mex+mey*mey+mez*mez;
        const float Lmo=mox*mox+moy*moy+moz*moz;

        float sphE = (mex*n2x+mey*n2y+mez*n2z) * rsqrtf(Lme*L2);
        float cphE = (n1x*n2x+n1y*n2y+n1z*n2z) * rsqrtf(L1*L2);
        { const float rn = rsqrtf(sphE*sphE + cphE*cphE); sphE *= rn; cphE *= rn; }
        float sthE, cthE; sincosf(th2.x, &sthE, &cthE);
        const float cE = cthE*cphE - sthE*sphE;
        const float sE = sthE*cphE + cthE*sphE;
        const float LjkE = v12x*v12x+v12y*v12y+v12z*v12z;
        const float invE = rsqrtf(fmaxf(LjkE, 1e-24f));
        Aff Bev = make_step(cE, sE, v12x*invE, v12y*invE, v12z*invE, A[3], A[4], A[5]);

        float sphO = (mox*n3x+moy*n3y+moz*n3z) * rsqrtf(Lmo*L3);
        float cphO = (n2x*n3x+n2y*n3y+n2z*n3z) * rsqrtf(L2*L3);
        { const float rn = rsqrtf(sphO*sphO + cphO*cphO); sphO *= rn; cphO *= rn; }
        float sthO, cthO; sincosf(th2.y, &sthO, &cthO);
        const float cO = cthO*cphO - sthO*sphO;
        const float sO_ = sthO*cphO + cthO*sphO;
        const float LjkO = v23x*v23x+v23y*v23y+v23z*v23z;
        const float invO = rsqrtf(fmaxf(LjkO, 1e-24f));
        Aff Bod = make_step(cO, sO_, v23x*invO, v23y*invO, v23z*invO, A[6], A[7], A[8]);

        Aff S = aff_compose(Bev, Bod);   // C_k = B_{2k}∘B_{2k+1}

        #pragma unroll
        for (int off = 1; off < 64; off <<= 1) {
            Aff Q; SHFL_AFF_UP(Q, S, off);
            if (lane >= off) S = aff_compose(Q, S);
        }
        Aff E; SHFL_AFF_UP(E, S, 1);
        if (lane == 0) { E.qw = 1.f; E.qx = E.qy = E.qz = 0.f; E.tx = E.ty = E.tz = 0.f; }
        Aff Pe = aff_compose(E, Bev);    // P_{2k}
        qnorm(Pe); qnorm(S);

        // emit atoms 2k+3, 2k+4 into sO
        {
            float ox, oy, oz;
            float* op = &sO[lane * 6 + 9];
            qrot(Pe.qw, Pe.qx, Pe.qy, Pe.qz, A[9], A[10], A[11], ox, oy, oz);
            op[0] = ox + Pe.tx; op[1] = oy + Pe.ty; op[2] = oz + Pe.tz;
            qrot(S.qw, S.qx, S.qy, S.qz, A[12], A[13], A[14], ox, oy, oz);
            op[3] = ox + S.tx;  op[4] = oy + S.ty;  op[5] = oz + S.tz;
        }
        if (lane < 9) sO[lane] = sA[lane];          // atoms 0..2 never move
        if (lane == 63) {                           // atom 131 + F matrix
            float ox, oy, oz;
            qrot(S.qw, S.qx, S.qy, S.qz, sA[393], sA[394], sA[395], ox, oy, oz);
            sO[393] = ox + S.tx; sO[394] = oy + S.ty; sO[395] = oz + S.tz;
            const float qw=S.qw, qx=S.qx, qy=S.qy, qz=S.qz;
            sF[0] = 1.f - 2.f*(qy*qy + qz*qz);
            sF[1] = 2.f*(qx*qy - qw*qz);
            sF[2] = 2.f*(qx*qz + qw*qy);
            sF[3] = 2.f*(qx*qy + qw*qz);
            sF[4] = 1.f - 2.f*(qx*qx + qz*qz);
            sF[5] = 2.f*(qy*qz - qw*qx);
            sF[6] = 2.f*(qx*qz - qw*qy);
            sF[7] = 2.f*(qy*qz + qw*qx);
            sF[8] = 1.f - 2.f*(qx*qx + qy*qy);
            sF[9] = S.tx; sF[10] = S.ty; sF[11] = S.tz;
        }
    }

    __syncthreads();

    if (wid == 0) {
        // store head (99 float4)
        const float4* sO4 = (const float4*)sO;
        ob4[lane] = sO4[lane];
        if (lane < 35) ob4[64 + lane] = sO4[64 + lane];
    } else if (isTail) {
        const float f00=sF[0], f01=sF[1], f02=sF[2];
        const float f10=sF[3], f11=sF[4], f12=sF[5];
        const float f20=sF[6], f21=sF[7], f22=sF[8];
        const float ftx=sF[9], fty=sF[10], ftz=sF[11];
        const float x0=T0.x, y0=T0.y, z0=T0.z;
        const float x1=T0.w, y1=T1.x, z1=T1.y;
        const float x2=T1.z, y2=T1.w, z2=T2.x;
        const float x3=T2.y, y3=T2.z, z3=T2.w;
        float4 o0, o1, o2;
        o0.x = f00*x0+f01*y0+f02*z0+ftx; o0.y = f10*x0+f11*y0+f12*z0+fty;
        o0.z = f20*x0+f21*y0+f22*z0+ftz; o0.w = f00*x1+f01*y1+f02*z1+ftx;
        o1.x = f10*x1+f11*y1+f12*z1+fty; o1.y = f20*x1+f21*y1+f22*z1+ftz;
        o1.z = f00*x2+f01*y2+f02*z2+ftx; o1.w = f10*x2+f11*y2+f12*z2+fty;
        o2.x = f20*x2+f21*y2+f22*z2+ftz; o2.y = f00*x3+f01*y3+f02*z3+ftx;
        o2.z = f10*x3+f11*y3+f12*z3+fty; o2.w = f20*x3+f21*y3+f22*z3+ftz;
        const int b = 99 + 3*t;
        ob4[b] = o0; ob4[b+1] = o1; ob4[b+2] = o2;
    }
}

extern "C" void kernel_launch(void* const* d_in, const int* in_sizes, int n_in,
                              void* d_out, int out_size, void* d_ws, size_t ws_size,
                              hipStream_t stream) {
    const float* theta = (const float*)d_in[0];  // input (N,K) fp32
    const float* pos0  = (const float*)d_in[1];  // pos0 (N,M,3) fp32
    float* out = (float*)d_out;                  // (N,M,3) fp32
    dihedral_block_kernel<<<NMOL, TPB, 0, stream>>>(theta, pos0, out);
}

// Round 9
// 18.889 us; speedup vs baseline: 3.8227x; 1.5100x over previous
//
#include <hip/hip_runtime.h>

// Dihedral2Coord — R6 structure (one molecule per WAVE, no barriers) with
// fast hardware trig (__sinf/__cosf -> v_sin_f32/v_cos_f32) replacing the
// libm sincosf CALL (full range-reduction, ~150+ instrs, the hidden VALU hog
// identified from R7's x6 measurement: VALUBusy 60% >> static op count).
//
// final[m] = P_{m-3}(pos0[m]); P_k = B_0∘...∘B_k with B_k the LOCAL-frame
// step rotation (dihedrals are rigid-invariant -> phi_k from pos0 alone).

#define NK 128
#define NM 512
#define NMOL 4096
#define TPB 256
#define MPW 4     // molecules (waves) per block

struct Aff { float qw, qx, qy, qz, tx, ty, tz; };

__device__ __forceinline__ void qrot(float qw, float qx, float qy, float qz,
                                     float vx, float vy, float vz,
                                     float& ox, float& oy, float& oz) {
    const float ux = qy*vz - qz*vy + qw*vx;
    const float uy = qz*vx - qx*vz + qw*vy;
    const float uz = qx*vy - qy*vx + qw*vz;
    ox = vx + 2.f*(qy*uz - qz*uy);
    oy = vy + 2.f*(qz*ux - qx*uz);
    oz = vz + 2.f*(qx*uy - qy*ux);
}

__device__ __forceinline__ Aff aff_compose(const Aff& Q, const Aff& P) {
    Aff r;
    r.qw = Q.qw*P.qw - Q.qx*P.qx - Q.qy*P.qy - Q.qz*P.qz;
    r.qx = Q.qw*P.qx + Q.qx*P.qw + Q.qy*P.qz - Q.qz*P.qy;
    r.qy = Q.qw*P.qy - Q.qx*P.qz + Q.qy*P.qw + Q.qz*P.qx;
    r.qz = Q.qw*P.qz + Q.qx*P.qy - Q.qy*P.qx + Q.qz*P.qw;
    float rx, ry, rz;
    qrot(Q.qw, Q.qx, Q.qy, Q.qz, P.tx, P.ty, P.tz, rx, ry, rz);
    r.tx = rx + Q.tx; r.ty = ry + Q.ty; r.tz = rz + Q.tz;
    return r;
}

__device__ __forceinline__ void qnorm(Aff& a) {
    const float r = rsqrtf(a.qw*a.qw + a.qx*a.qx + a.qy*a.qy + a.qz*a.qz);
    a.qw *= r; a.qx *= r; a.qy *= r; a.qz *= r;
}

__device__ __forceinline__ Aff make_step(float c, float s,
                                         float ax, float ay, float az,
                                         float px, float py, float pz) {
    const float hc = sqrtf(fmaxf(0.f, 0.5f*(1.f + c)));
    const float hs = copysignf(sqrtf(fmaxf(0.f, 0.5f*(1.f - c))), s);
    Aff b; b.qw = hc; b.qx = hs*ax; b.qy = hs*ay; b.qz = hs*az;
    float rx, ry, rz;
    qrot(b.qw, b.qx, b.qy, b.qz, px, py, pz, rx, ry, rz);
    b.tx = px - rx; b.ty = py - ry; b.tz = pz - rz;
    return b;
}

#define SHFL_AFF_UP(D, S, off)                                           \
    D.qw = __shfl_up(S.qw, off, 64); D.qx = __shfl_up(S.qx, off, 64);    \
    D.qy = __shfl_up(S.qy, off, 64); D.qz = __shfl_up(S.qz, off, 64);    \
    D.tx = __shfl_up(S.tx, off, 64); D.ty = __shfl_up(S.ty, off, 64);    \
    D.tz = __shfl_up(S.tz, off, 64);

__global__ __launch_bounds__(TPB, 4) void dihedral_fused_kernel(
    const float* __restrict__ theta,  // (NMOL, NK)
    const float* __restrict__ pos0,   // (NMOL, NM, 3)
    float* __restrict__ out)          // (NMOL, NM, 3)
{
    const int tid  = threadIdx.x;
    const int lane = tid & 63;
    const int wid  = tid >> 6;
    const int mol  = blockIdx.x * MPW + wid;
    const float4* __restrict__ pb4 = (const float4*)(pos0 + (size_t)mol * (NM*3));
    float4*       __restrict__ ob4 = (float4*)(out  + (size_t)mol * (NM*3));

    __shared__ float sA[MPW][400];   // per-wave: pos0 atoms 0..131
    __shared__ float sO[MPW][400];   // per-wave: final atoms 0..131

    // ---- issue ALL global loads up front ----
    float4 h0 = pb4[lane];
    float4 h1; if (lane < 35) h1 = pb4[64 + lane];
    const float2 th2 = ((const float2*)(theta + (size_t)mol * NK))[lane];
    float4 Ta0, Ta1, Ta2, Tb0, Tb1, Tb2;
    { const int b = 99 + 3*lane; Ta0 = pb4[b]; Ta1 = pb4[b+1]; Ta2 = pb4[b+2]; }
    const bool hasB = (lane < 31);   // tasks 64..94
    if (hasB) { const int b = 99 + 3*(64 + lane); Tb0 = pb4[b]; Tb1 = pb4[b+1]; Tb2 = pb4[b+2]; }

    // stage head into this wave's LDS slice (same-wave DS ordering, no barrier)
    float4* sA4 = (float4*)sA[wid];
    sA4[lane] = h0;
    if (lane < 35) sA4[64 + lane] = h1;

    // lane k: atoms 2k..2k+4 (15 floats)
    float A[16];
    const float2* ap2 = (const float2*)&sA[wid][lane * 6];
    #pragma unroll
    for (int i = 0; i < 7; ++i) { const float2 v = ap2[i]; A[2*i] = v.x; A[2*i+1] = v.y; }
    A[14] = sA[wid][lane * 6 + 14];

    // ---- dihedral geometry for steps 2k (even) and 2k+1 (odd), shared ----
    const float v01x=A[3]-A[0],  v01y=A[4]-A[1],   v01z=A[5]-A[2];
    const float v12x=A[6]-A[3],  v12y=A[7]-A[4],   v12z=A[8]-A[5];
    const float v23x=A[9]-A[6],  v23y=A[10]-A[7],  v23z=A[11]-A[8];
    const float v34x=A[12]-A[9], v34y=A[13]-A[10], v34z=A[14]-A[11];
    const float n1x=v01y*v12z-v01z*v12y, n1y=v01z*v12x-v01x*v12z, n1z=v01x*v12y-v01y*v12x;
    const float n2x=v12y*v23z-v12z*v23y, n2y=v12z*v23x-v12x*v23z, n2z=v12x*v23y-v12y*v23x;
    const float n3x=v23y*v34z-v23z*v34y, n3y=v23z*v34x-v23x*v34z, n3z=v23x*v34y-v23y*v34x;
    const float mex=n1y*v12z-n1z*v12y,  mey=n1z*v12x-n1x*v12z,  mez=n1x*v12y-n1y*v12x;
    const float mox=n2y*v23z-n2z*v23y,  moy=n2z*v23x-n2x*v23z,  moz=n2x*v23y-n2y*v23x;
    const float L1=n1x*n1x+n1y*n1y+n1z*n1z;
    const float L2=n2x*n2x+n2y*n2y+n2z*n2z;
    const float L3=n3x*n3x+n3y*n3y+n3z*n3z;
    const float Lme=mex*mex+mey*mey+mez*mez;
    const float Lmo=mox*mox+moy*moy+moz*moz;

    // even step 2k  (fast HW trig: v_sin/v_cos, |theta| small)
    float sphE = (mex*n2x+mey*n2y+mez*n2z) * rsqrtf(Lme*L2);
    float cphE = (n1x*n2x+n1y*n2y+n1z*n2z) * rsqrtf(L1*L2);
    { const float rn = rsqrtf(sphE*sphE + cphE*cphE); sphE *= rn; cphE *= rn; }
    const float sthE = __sinf(th2.x), cthE = __cosf(th2.x);
    const float cE = cthE*cphE - sthE*sphE;
    const float sE = sthE*cphE + cthE*sphE;
    const float LjkE = v12x*v12x+v12y*v12y+v12z*v12z;
    const float invE = rsqrtf(fmaxf(LjkE, 1e-24f));
    Aff Bev = make_step(cE, sE, v12x*invE, v12y*invE, v12z*invE, A[3], A[4], A[5]);

    // odd step 2k+1 (n1' = n2, reuses shared normals)
    float sphO = (mox*n3x+moy*n3y+moz*n3z) * rsqrtf(Lmo*L3);
    float cphO = (n2x*n3x+n2y*n3y+n2z*n3z) * rsqrtf(L2*L3);
    { const float rn = rsqrtf(sphO*sphO + cphO*cphO); sphO *= rn; cphO *= rn; }
    const float sthO = __sinf(th2.y), cthO = __cosf(th2.y);
    const float cO = cthO*cphO - sthO*sphO;
    const float sO_ = sthO*cphO + cthO*sphO;
    const float LjkO = v23x*v23x+v23y*v23y+v23z*v23z;
    const float invO = rsqrtf(fmaxf(LjkO, 1e-24f));
    Aff Bod = make_step(cO, sO_, v23x*invO, v23y*invO, v23z*invO, A[6], A[7], A[8]);

    Aff S = aff_compose(Bev, Bod);   // C_k = B_{2k}∘B_{2k+1}

    // ---- wave-inclusive scan: S -> P_{2k+1} ----
    #pragma unroll
    for (int off = 1; off < 64; off <<= 1) {
        Aff Q; SHFL_AFF_UP(Q, S, off);
        if (lane >= off) S = aff_compose(Q, S);
    }
    Aff E; SHFL_AFF_UP(E, S, 1);
    if (lane == 0) { E.qw = 1.f; E.qx = E.qy = E.qz = 0.f; E.tx = E.ty = E.tz = 0.f; }
    Aff Pe = aff_compose(E, Bev);    // P_{2k}
    qnorm(Pe); qnorm(S);

    // ---- emit head atoms into this wave's sO slice ----
    {
        float ox, oy, oz;
        float* op = &sO[wid][lane * 6 + 9];
        qrot(Pe.qw, Pe.qx, Pe.qy, Pe.qz, A[9], A[10], A[11], ox, oy, oz);
        op[0] = ox + Pe.tx; op[1] = oy + Pe.ty; op[2] = oz + Pe.tz;
        qrot(S.qw, S.qx, S.qy, S.qz, A[12], A[13], A[14], ox, oy, oz);
        op[3] = ox + S.tx;  op[4] = oy + S.ty;  op[5] = oz + S.tz;
    }
    if (lane < 9) sO[wid][lane] = sA[wid][lane];   // atoms 0..2 never move
    if (lane == 63) {                               // atom 131 = P_127(pos0[131])
        float ox, oy, oz;
        qrot(S.qw, S.qx, S.qy, S.qz, sA[wid][393], sA[wid][394], sA[wid][395], ox, oy, oz);
        sO[wid][393] = ox + S.tx; sO[wid][394] = oy + S.ty; sO[wid][395] = oz + S.tz;
    }

    // ---- F = P_127 broadcast from lane 63 (register-only) ----
    Aff F;
    F.qw = __shfl(S.qw, 63, 64); F.qx = __shfl(S.qx, 63, 64);
    F.qy = __shfl(S.qy, 63, 64); F.qz = __shfl(S.qz, 63, 64);
    F.tx = __shfl(S.tx, 63, 64); F.ty = __shfl(S.ty, 63, 64);
    F.tz = __shfl(S.tz, 63, 64);
    const float f00 = 1.f - 2.f*(F.qy*F.qy + F.qz*F.qz);
    const float f01 = 2.f*(F.qx*F.qy - F.qw*F.qz);
    const float f02 = 2.f*(F.qx*F.qz + F.qw*F.qy);
    const float f10 = 2.f*(F.qx*F.qy + F.qw*F.qz);
    const float f11 = 1.f - 2.f*(F.qx*F.qx + F.qz*F.qz);
    const float f12 = 2.f*(F.qy*F.qz - F.qw*F.qx);
    const float f20 = 2.f*(F.qx*F.qz - F.qw*F.qy);
    const float f21 = 2.f*(F.qy*F.qz + F.qw*F.qx);
    const float f22 = 1.f - 2.f*(F.qx*F.qx + F.qy*F.qy);

    // ---- store head (99 float4 from this wave's sO) ----
    const float4* sO4 = (const float4*)sO[wid];
    ob4[lane] = sO4[lane];
    if (lane < 35) ob4[64 + lane] = sO4[64 + lane];

    // ---- tail: 95 f4-triples (atoms 132..511), data already in registers ----
    #define TAIL_EMIT(b, va, vb, vc)                                          \
    do {                                                                      \
        const float x0=va.x, y0=va.y, z0=va.z;                                \
        const float x1=va.w, y1=vb.x, z1=vb.y;                                \
        const float x2=vb.z, y2=vb.w, z2=vc.x;                                \
        const float x3=vc.y, y3=vc.z, z3=vc.w;                                \
        float4 o0, o1, o2;                                                    \
        o0.x = f00*x0+f01*y0+f02*z0+F.tx; o0.y = f10*x0+f11*y0+f12*z0+F.ty;   \
        o0.z = f20*x0+f21*y0+f22*z0+F.tz; o0.w = f00*x1+f01*y1+f02*z1+F.tx;   \
        o1.x = f10*x1+f11*y1+f12*z1+F.ty; o1.y = f20*x1+f21*y1+f22*z1+F.tz;   \
        o1.z = f00*x2+f01*y2+f02*z2+F.tx; o1.w = f10*x2+f11*y2+f12*z2+F.ty;   \
        o2.x = f20*x2+f21*y2+f22*z2+F.tz; o2.y = f00*x3+f01*y3+f02*z3+F.tx;   \
        o2.z = f10*x3+f11*y3+f12*z3+F.ty; o2.w = f20*x3+f21*y3+f22*z3+F.tz;   \
        ob4[(b)] = o0; ob4[(b)+1] = o1; ob4[(b)+2] = o2;                      \
    } while (0)

    TAIL_EMIT(99 + 3*lane, Ta0, Ta1, Ta2);
    if (hasB) TAIL_EMIT(99 + 3*(64 + lane), Tb0, Tb1, Tb2);
    #undef TAIL_EMIT
}

extern "C" void kernel_launch(void* const* d_in, const int* in_sizes, int n_in,
                              void* d_out, int out_size, void* d_ws, size_t ws_size,
                              hipStream_t stream) {
    const float* theta = (const float*)d_in[0];  // input (N,K) fp32
    const float* pos0  = (const float*)d_in[1];  // pos0 (N,M,3) fp32
    float* out = (float*)d_out;                  // (N,M,3) fp32
    dihedral_fused_kernel<<<NMOL / MPW, TPB, 0, stream>>>(theta, pos0, out);
}